// Round 13
// baseline (280.145 us; speedup 1.0000x reference)
//
#include <hip/hip_runtime.h>
#include <hip/hip_bf16.h>

// CausalSelfAttention on MI355X. fp32 in / fp32 out, bf16 MFMA compute.
// [0] merged cvt pre-pass: {x, w_qkv, w_out} -> bf16 (single launch)
// [1] QKV GEMM: 128^2 counted-vmcnt 2-phase (R11 exact: 72.9us measured; the
//     256x128-tile variant regressed 81us via residency loss -> reverted)
// [2] flash attention: 4-wave blocks, 32 q-rows/wave, 32x32 MFMA QK^T with
//     IN-REGISTER softmax->PV (T12): P packed to bf16 via packtr pairs +
//     v_permlane32_swap_b32 reassembles PV A-frags; NO Ps LDS (18.4KB total),
//     lsum via ones-MFMA (osum rows = o rows), masked-kt MFMA skip, balanced
//     qt map, v_perm V-transpose, rotated K/V prefetch, setprio PV, PV ks-skip
// [3] out projection via same 128^2 kernel -> d_out fp32
// B=4 T=2048 C=1024 H=16 Dh=64.

#define D_MODEL 1024
#define N_HEADS 16
#define HEAD_DIM 64
#define SEQ 2048
#define BATCH 4

typedef __attribute__((ext_vector_type(8))) short bf16x8;
typedef __attribute__((ext_vector_type(4))) float f32x4;
typedef __attribute__((ext_vector_type(16))) float f32x16;
typedef unsigned int uint;

__device__ __forceinline__ short f2bf(float f) {
    union { float f; uint i; } c; c.f = f;
    uint x = c.i;
    x += 0x7fffu + ((x >> 16) & 1u);   // RNE
    return (short)(x >> 16);
}
__device__ __forceinline__ uint pack2(float a, float b) {
    return (uint)(unsigned short)f2bf(a) | ((uint)(unsigned short)f2bf(b) << 16);
}
__device__ __forceinline__ uint asu(float f) { union { float f; uint i; } c; c.f = f; return c.i; }
// truncating pack of two f32 -> bf16x2 (single v_perm); word = [lo16(bf(a)) | hi16(bf(b))]
__device__ __forceinline__ uint packtr(float lo, float hi) {
    return __builtin_amdgcn_perm(asu(hi), asu(lo), 0x07060302u);
}

// async global->LDS, 16B per lane; LDS dest = wave-uniform base + lane*16
__device__ __forceinline__ void glds16(const void* g, void* l) {
    __builtin_amdgcn_global_load_lds(
        (const __attribute__((address_space(1))) uint*)g,
        (__attribute__((address_space(3))) uint*)l, 16, 0, 0);
}

// ---------- fp32 -> bf16, 3 sources -> contiguous dst ----------
__global__ __launch_bounds__(256) void cvt3_bf16(const float* __restrict__ s0,
                                                 const float* __restrict__ s1,
                                                 const float* __restrict__ s2,
                                                 short* __restrict__ dst,
                                                 int n0, int n01) {
    int i = blockIdx.x * 256 + threadIdx.x;    // vec4 index
    const float* src;
    int off;
    if (i < n0)       { src = s0; off = i; }
    else if (i < n01) { src = s1; off = i - n0; }
    else              { src = s2; off = i - n01; }
    float4 f = *(const float4*)(src + (size_t)off * 4);
    uint2 o; o.x = pack2(f.x, f.y); o.y = pack2(f.z, f.w);
    *(uint2*)(dst + (size_t)i * 4) = o;
}

// ---------- GEMM: C[M,N] = A[M,K]@B[N,K]^T + bias ---------- (R11 exact)
// Counted-vmcnt 2-phase: per tile t: s_barrier (WAR, no vm drain) ->
// STAGE(t+1) into freed buf -> s_waitcnt vmcnt(8) -> ds_read frags -> MFMA.
// MODE 0: fp32 out. MODE 1: bf16 scatter q/k/v [B,H,T,Dh].
template <int MODE>
__global__ __launch_bounds__(256, 2) void gemm_bt(
    const short* __restrict__ A, const short* __restrict__ B,
    const float* __restrict__ bias, float* __restrict__ Cp,
    int M, int N, int K,
    short* __restrict__ qp, short* __restrict__ kp, short* __restrict__ vp)
{
    __shared__ short As[2][128][32];   // unpadded: glds needs contiguous lane*16 dest
    __shared__ short Bs[2][128][32];
    const int tid = threadIdx.x;
    const int wave = tid >> 6, lane = tid & 63;
    const int quad = lane >> 4, l16 = lane & 15;
    const int wm = (wave >> 1) * 64, wn = (wave & 1) * 64;
    const int rowBase = blockIdx.y * 128;
    const int colBase = blockIdx.x * 128;

    const short* gA = A + (size_t)(rowBase + wave * 32 + (lane >> 2)) * K + (lane & 3) * 8;
    const short* gB = B + (size_t)(colBase + wave * 32 + (lane >> 2)) * K + (lane & 3) * 8;

    f32x4 acc[4][4] = {};
    const int NT = K / 32;

#define GSTAGE(buf, k0)                                                \
    {                                                                  \
        glds16(gA + (k0), &As[buf][wave * 32][0]);                     \
        glds16(gA + (size_t)16 * K + (k0), &As[buf][wave * 32 + 16][0]); \
        glds16(gB + (k0), &Bs[buf][wave * 32][0]);                     \
        glds16(gB + (size_t)16 * K + (k0), &Bs[buf][wave * 32 + 16][0]); \
    }

    GSTAGE(0, 0)

    for (int t = 0; t < NT; ++t) {
        const int cur = t & 1;
        __builtin_amdgcn_s_barrier();              // WAR rendezvous (no vm drain)
        __builtin_amdgcn_sched_barrier(0);
        if (t + 1 < NT) GSTAGE(cur ^ 1, (t + 1) * 32)   // fly across this iter
        __builtin_amdgcn_sched_barrier(0);
        if (t + 1 < NT) asm volatile("s_waitcnt vmcnt(8)" ::: "memory");
        else            asm volatile("s_waitcnt vmcnt(0)" ::: "memory");
        __builtin_amdgcn_sched_barrier(0);

        bf16x8 af[4], bfr[4];
#pragma unroll
        for (int i = 0; i < 4; ++i)
            af[i] = *(const bf16x8*)&As[cur][wm + i * 16 + l16][quad * 8];
#pragma unroll
        for (int j = 0; j < 4; ++j)
            bfr[j] = *(const bf16x8*)&Bs[cur][wn + j * 16 + l16][quad * 8];
        __builtin_amdgcn_s_setprio(1);
#pragma unroll
        for (int i = 0; i < 4; ++i)
#pragma unroll
            for (int j = 0; j < 4; ++j)
                acc[i][j] = __builtin_amdgcn_mfma_f32_16x16x32_bf16(af[i], bfr[j], acc[i][j], 0, 0, 0);
        __builtin_amdgcn_s_setprio(0);
    }
#undef GSTAGE

#pragma unroll
    for (int i = 0; i < 4; ++i) {
#pragma unroll
        for (int j = 0; j < 4; ++j) {
#pragma unroll
            for (int r = 0; r < 4; ++r) {
                int row = rowBase + wm + i * 16 + quad * 4 + r;   // C/D: row=quad*4+reg
                int col = colBase + wn + j * 16 + l16;            //       col=lane&15
                float v = acc[i][j][r] + bias[col];
                if (MODE == 0) {
                    Cp[(size_t)row * N + col] = v;
                } else {
                    int which = col >> 10;          // 0:q 1:k 2:v
                    int h = (col >> 6) & 15;
                    int d = col & 63;
                    int b = row >> 11;
                    int t2 = row & 2047;
                    short* dst = (which == 0) ? qp : (which == 1) ? kp : vp;
                    dst[((((size_t)b * N_HEADS + h) * SEQ) + t2) * HEAD_DIM + d] = f2bf(v);
                }
            }
        }
    }
}

// ---------- flash attention (32x32 MFMA, in-register P) ----------
// grid dim3(B*H=64, 16). Balanced qt map (per-CU-class work equalized).
// block = 256 threads = 4 waves; wave owns 32 q-rows.
// QK^T: S^T = MFMA32(A=K-frag, B=Q-frag): D[row=key][col=q]; lane (l31,hi)
// holds P[q=l31][key=crow(r,hi)], crow=(r&3)+8*(r>>2)+4*hi -- q-row lane-local.
// Softmax in-register; pack pairs (packtr) -> c0..c7; v_permlane32_swap_b32
// (c0,c2)(c1,c3) builds pa[2kt] words 0..3, (c4,c6)(c5,c7) -> pa[2kt+1]:
// exact PV A-frags A[row=q=l31][k=ks*16+hi*8+j]. No Ps LDS.
// PV: O[q][d] = MFMA32(pa[ks], Vt-frag B[k=key][col=d]); lsum via ones-MFMA
// (osum rows = crow = o rows -> per-lane normalize).
// Per-kt: fully-masked -> skip (PV breaks first); clean -> no mask VALU;
// diagonal -> per-element select. Conditions scalarized via readfirstlane.
__global__ __launch_bounds__(256, 4) void attn_fwd(
    const short* __restrict__ Q, const short* __restrict__ K,
    const short* __restrict__ V, short* __restrict__ O)
{
    __shared__ short Ks[64][72];    // [key][d]
    __shared__ short Vt[64][72];    // [d][key]
    const int tid = threadIdx.x;
    const int wave = tid >> 6, lane = tid & 63;
    const int l31 = lane & 31, hi = lane >> 5;
    const int bh = blockIdx.x;
    const int b = bh >> 4, h = bh & 15;
    const int y = blockIdx.y, y0 = y & 3, g = y >> 2;
    const int qt = (g == 0) ? 15 - y0 : (g == 1) ? 8 + y0 : (g == 2) ? 7 - y0 : y0;
    const int qbase = qt * 128;
    const short* Qh = Q + (size_t)bh * SEQ * HEAD_DIM;
    const short* Kh = K + (size_t)bh * SEQ * HEAD_DIM;
    const short* Vh = V + (size_t)bh * SEQ * HEAD_DIM;

    const float C1 = 0.125f * 1.44269504f;   // scale * log2(e)
    const float C2 = 14.4269504f;            // 10 * log2(e)

    // constant bf16 1.0 B-fragment for the row-sum MFMA
    bf16x8 onesf;
#pragma unroll
    for (int e = 0; e < 8; ++e) onesf[e] = (short)0x3F80;

    // Q B-frags: B[k=d][col=q=l31]: Q[qbase+w*32+l31][ks*16 + hi*8 .. +7]
    bf16x8 qf[4];
#pragma unroll
    for (int ks = 0; ks < 4; ++ks)
        qf[ks] = *(const bf16x8*)(Qh + (size_t)(qbase + wave * 32 + l31) * HEAD_DIM + ks * 16 + hi * 8);

    f32x16 o[2] = {};               // [dtile]; rows q=crow(r,hi), col d=dt*32+l31
    f32x16 osum = {};               // P@1 row-sums, same row layout as o

    const int subw = qbase + wave * 32;                  // wave's first q row
    const int subS = __builtin_amdgcn_readfirstlane(subw);
    const int qrow = subS + l31;                         // this lane's q row

    const int kr = tid >> 2, kc = (tid & 3) * 16;        // K staging: row, col
    const int vk = (tid & 31) * 2, vd = (tid >> 5) * 8;  // V staging: key pair, d base

    const int ntiles = 2 * qt + 2;
    // preload tile 0
    int4 kv0 = *(const int4*)(Kh + (size_t)kr * HEAD_DIM + kc);
    int4 kv1 = *(const int4*)(Kh + (size_t)kr * HEAD_DIM + kc + 8);
    int4 vv0 = *(const int4*)(Vh + (size_t)vk * HEAD_DIM + vd);
    int4 vv1 = *(const int4*)(Vh + (size_t)(vk + 1) * HEAD_DIM + vd);

    for (int j = 0; j < ntiles; ++j) {
        const int kb = j * 64;
        __syncthreads();                 // prior tile fully consumed
        *(int4*)&Ks[kr][kc] = kv0;
        *(int4*)&Ks[kr][kc + 8] = kv1;
        {   // V transpose: v_perm pack (1 op/word), paired b32 writes
            const uint* pa_ = (const uint*)&vv0;
            const uint* pb_ = (const uint*)&vv1;
#pragma unroll
            for (int e = 0; e < 4; ++e) {
                uint lo = __builtin_amdgcn_perm(pb_[e], pa_[e], 0x05040100u);
                uint hi2 = __builtin_amdgcn_perm(pb_[e], pa_[e], 0x07060302u);
                *(uint*)&Vt[vd + 2 * e][vk] = lo;
                *(uint*)&Vt[vd + 2 * e + 1][vk] = hi2;
            }
        }
        __syncthreads();

        // rotated prefetch: next tile's K/V loads overlap this tile's compute
        if (j + 1 < ntiles) {
            const int kbn = kb + 64;
            kv0 = *(const int4*)(Kh + (size_t)(kbn + kr) * HEAD_DIM + kc);
            kv1 = *(const int4*)(Kh + (size_t)(kbn + kr) * HEAD_DIM + kc + 8);
            vv0 = *(const int4*)(Vh + (size_t)(kbn + vk) * HEAD_DIM + vd);
            vv1 = *(const int4*)(Vh + (size_t)(kbn + vk + 1) * HEAD_DIM + vd);
        }

        if (kb > subS + 31) continue;   // whole wave's rows masked for this tile

        // QK^T + in-register softmax + pack/swap -> pa[4]
        bf16x8 pa[4];
#pragma unroll
        for (int kt = 0; kt < 2; ++kt) {
            const int base = kb + kt * 32;      // scalar
            if (base > subS + 31) continue;     // kt fully masked (PV breaks first)
            f32x16 s = {};
#pragma unroll
            for (int ks = 0; ks < 4; ++ks) {
                bf16x8 kf = *(const bf16x8*)&Ks[kt * 32 + l31][ks * 16 + hi * 8];
                s = __builtin_amdgcn_mfma_f32_32x32x16_bf16(kf, qf[ks], s, 0, 0, 0);
            }
            uint c[8];
            if (base + 31 <= subS) {            // fully unmasked: no mask VALU
#pragma unroll
                for (int pr = 0; pr < 8; ++pr) {
                    float plo = __builtin_exp2f(__builtin_fmaf(s[2 * pr], C1, -C2));
                    float phi = __builtin_exp2f(__builtin_fmaf(s[2 * pr + 1], C1, -C2));
                    c[pr] = packtr(plo, phi);
                }
            } else {                            // diagonal subtile
                const int khi = base + 4 * hi;
                float p[16];
#pragma unroll
                for (int r = 0; r < 16; ++r) {
                    float a = __builtin_fmaf(s[r], C1, -C2);
                    if (khi + (r & 3) + 8 * (r >> 2) > qrow) a = -1e30f;
                    p[r] = __builtin_exp2f(a);
                }
#pragma unroll
                for (int pr = 0; pr < 8; ++pr) c[pr] = packtr(p[2 * pr], p[2 * pr + 1]);
            }
            // cross-half reassembly: after swap, c0..c3 = words 0..3 of pa[2kt],
            // c4..c7 = words 0..3 of pa[2kt+1]
            asm volatile("v_permlane32_swap_b32 %0, %1" : "+v"(c[0]), "+v"(c[2]));
            asm volatile("v_permlane32_swap_b32 %0, %1" : "+v"(c[1]), "+v"(c[3]));
            asm volatile("v_permlane32_swap_b32 %0, %1" : "+v"(c[4]), "+v"(c[6]));
            asm volatile("v_permlane32_swap_b32 %0, %1" : "+v"(c[5]), "+v"(c[7]));
            uint4 u0; u0.x = c[0]; u0.y = c[1]; u0.z = c[2]; u0.w = c[3];
            uint4 u1; u1.x = c[4]; u1.y = c[5]; u1.z = c[6]; u1.w = c[7];
            pa[2 * kt] = *(bf16x8*)&u0;
            pa[2 * kt + 1] = *(bf16x8*)&u1;
        }

        // O += P @ V ; osum += P @ 1 (ks = 16-key slots, break past masked)
#pragma unroll
        for (int ks = 0; ks < 4; ++ks) {
            if (kb + ks * 16 > subS + 31) break;
            __builtin_amdgcn_s_setprio(1);
            osum = __builtin_amdgcn_mfma_f32_32x32x16_bf16(pa[ks], onesf, osum, 0, 0, 0);
#pragma unroll
            for (int dt = 0; dt < 2; ++dt) {
                bf16x8 vf = *(const bf16x8*)&Vt[dt * 32 + l31][ks * 16 + hi * 8];
                o[dt] = __builtin_amdgcn_mfma_f32_32x32x16_bf16(pa[ks], vf, o[dt], 0, 0, 0);
            }
            __builtin_amdgcn_s_setprio(0);
        }
    }

    // epilogue: per-lane normalize (osum[r] is denominator for q=crow(r,hi),
    // same row o[dt][r] holds), store
#pragma unroll
    for (int r = 0; r < 16; ++r) {
        float inv = 1.f / osum[r];
        int t = qbase + wave * 32 + (r & 3) + 8 * (r >> 2) + 4 * hi;
        size_t base = ((size_t)b * SEQ + t) * D_MODEL + h * HEAD_DIM;
#pragma unroll
        for (int dt = 0; dt < 2; ++dt)
            O[base + dt * 32 + l31] = f2bf(o[dt][r] * inv);
    }
}

extern "C" void kernel_launch(void* const* d_in, const int* in_sizes, int n_in,
                              void* d_out, int out_size, void* d_ws, size_t ws_size,
                              hipStream_t stream)
{
    const float* x     = (const float*)d_in[0];
    const float* w_qkv = (const float*)d_in[1];
    const float* b_qkv = (const float*)d_in[2];
    const float* w_out = (const float*)d_in[3];
    const float* b_out = (const float*)d_in[4];
    float* out = (float*)d_out;

    const int NX = BATCH * SEQ * D_MODEL;          // 8388608
    const int NWQ = 3 * D_MODEL * D_MODEL;
    const int NWO = D_MODEL * D_MODEL;
    const size_t HE = (size_t)BATCH * N_HEADS * SEQ * HEAD_DIM;

    short* xb    = (short*)d_ws;
    short* wqkvb = xb + NX;
    short* woutb = wqkvb + NWQ;
    short* qp    = woutb + NWO;
    short* kp    = qp + HE;
    short* vp    = kp + HE;
    short* ho    = xb;                   // aliases xb (dead after GEMM1)

    const int M = BATCH * SEQ;  // 8192

    // merged cvt: xb|wqkvb|woutb are contiguous in ws; one launch
    cvt3_bf16<<<(NX + NWQ + NWO) / 1024, 256, 0, stream>>>(
        x, w_qkv, w_out, xb, NX / 4, (NX + NWQ) / 4);

    gemm_bt<1><<<dim3(3 * D_MODEL / 128, M / 128), 256, 0, stream>>>(
        xb, wqkvb, b_qkv, nullptr, M, 3 * D_MODEL, D_MODEL, qp, kp, vp);

    attn_fwd<<<dim3(BATCH * N_HEADS, SEQ / 128), 256, 0, stream>>>(qp, kp, vp, ho);

    gemm_bt<0><<<dim3(D_MODEL / 128, M / 128), 256, 0, stream>>>(
        ho, woutb, b_out, out, M, D_MODEL, D_MODEL, nullptr, nullptr, nullptr);
}